// Round 11
// baseline (802.644 us; speedup 1.0000x reference)
//
#include <hip/hip_runtime.h>
#include <hip/hip_fp16.h>

// RNAGNN round 17: pair-split gather (16 lanes/node). Every prior variant
// (L2-resident two-pass, 4-deep ILP, nt) left per-pass time ~83-89 us; the
// invariant is 2 divergent line-transactions per edge (~4 cyc/trans at L1).
// Now lane pairs split each 32B z row into two adjacent 16B loads that
// coalesce into ONE line-request per edge. Epilogue: one output feat per
// lane (16 FMA, no post-matmul shuffles, coalesced scalar stores) after a
// single xor-1 parity exchange. 2-deep pipeline. BIN_CHUNK stays 4096.

#define DIM 16
#define F_IN 64
#define BUCK_SHIFT 10
#define BUCK_SIZE 1024
#define MAXB 256            // nb = ceil(200000/1024) = 196
#define HIST_CHUNK 4096
#define BIN_CHUNK 4096
#define EPB 16              // edges per thread in bin (4096/256)
#define CSR_CAP 33280       // staging words: mean 32653 + ~3.5 sigma; fallback beyond

// LDS weight layout: W[f][j] at f*17+j -> lanes with distinct f hit distinct banks
#define WA_OFF 0
#define WB_OFF 272
#define BA_OFF 544
#define BB_OFF 560
#define SW_SIZE 576
#define WIDX(f, j) ((f) * 17 + (j))

// ---------------- per-bucket edge histogram ----------------

__global__ void hist_kernel(const int* __restrict__ dst, int* __restrict__ ghist,
                            int E, int nb) {
    __shared__ int lh[MAXB];
    int t = threadIdx.x;
    for (int i = t; i < nb; i += 256) lh[i] = 0;
    __syncthreads();
    int base = blockIdx.x * HIST_CHUNK;
    int end = min(base + HIST_CHUNK, E);
    for (int e = base + t; e < end; e += 256) atomicAdd(&lh[dst[e] >> BUCK_SHIFT], 1);
    __syncthreads();
    for (int b = t; b < nb; b += 256) {
        int c = lh[b];
        if (c) atomicAdd(&ghist[b], c);
    }
}

// exclusive scan of ghist (nb <= 256) -> boff, cursor
__global__ void scan_kernel(const int* __restrict__ ghist, int* __restrict__ boff,
                            int* __restrict__ cursor, int nb, int E) {
    __shared__ int sd[256];
    int t = threadIdx.x;
    int v = (t < nb) ? ghist[t] : 0;
    sd[t] = v;
    __syncthreads();
    for (int off = 1; off < 256; off <<= 1) {
        int u = (t >= off) ? sd[t - off] : 0;
        __syncthreads();
        sd[t] += u;
        __syncthreads();
    }
    if (t < nb) {
        int excl = sd[t] - v;
        boff[t] = excl;
        cursor[t] = excl;
    }
    if (t == 255) boff[nb] = E;
}

// pass A: bin edges into dst-range buckets; packed = src | (local_dst << 18).
// LDS bucket-sort within the block, then linear (coalesced) flush to global.
__launch_bounds__(256)
__global__ void bin_kernel(const int* __restrict__ src, const int* __restrict__ dst,
                           int* __restrict__ cursor, unsigned* __restrict__ packed,
                           int E, int nb) {
    __shared__ unsigned sedge[BIN_CHUNK];        // 16 KB sorted packed values
    __shared__ unsigned char sbid[BIN_CHUNK];    // 4 KB bucket id per slot
    __shared__ int lh[MAXB];
    __shared__ int sd[MAXB];
    __shared__ int lstart[MAXB];
    __shared__ int lrank[MAXB];
    __shared__ int gbase[MAXB];

    int t = threadIdx.x;
    int base = blockIdx.x * BIN_CHUNK;
    int end = min(base + BIN_CHUNK, E);
    lh[t] = 0;
    __syncthreads();

    unsigned pv[EPB];
    int bk[EPB];
#pragma unroll
    for (int i = 0; i < EPB; ++i) {
        int e = base + t + i * 256;
        if (e < end) {
            int d = dst[e];
            int b = d >> BUCK_SHIFT;
            pv[i] = (unsigned)src[e] | ((unsigned)(d & (BUCK_SIZE - 1)) << 18);
            bk[i] = b;
            atomicAdd(&lh[b], 1);
        } else {
            bk[i] = -1;
            pv[i] = 0u;
        }
    }
    __syncthreads();

    int v = (t < nb) ? lh[t] : 0;
    sd[t] = v;
    __syncthreads();
    for (int off = 1; off < 256; off <<= 1) {
        int u = (t >= off) ? sd[t - off] : 0;
        __syncthreads();
        sd[t] += u;
        __syncthreads();
    }
    if (t < nb) {
        lstart[t] = sd[t] - v;
        lrank[t] = 0;
        gbase[t] = v ? atomicAdd(&cursor[t], v) : 0;
    }
    __syncthreads();

#pragma unroll
    for (int i = 0; i < EPB; ++i) {
        int b = bk[i];
        if (b >= 0) {
            int rank = atomicAdd(&lrank[b], 1);
            int p = lstart[b] + rank;
            sedge[p] = pv[i];
            sbid[p] = (unsigned char)b;
        }
    }
    __syncthreads();

    int total = end - base;
    for (int j = t; j < total; j += 256) {
        int b = sbid[j];
        packed[(size_t)gbase[b] + (unsigned)(j - lstart[b])] = sedge[j];
    }
}

// pass B: bucket -> exact CSR via LDS staging (coalesced col writes).
// Dynamic LDS: sstage[CSR_CAP] (sd aliases it) + cnt[1024] + scur[1024].
__launch_bounds__(1024)
__global__ void csr_kernel(const unsigned* __restrict__ packed, const int* __restrict__ boff,
                           int* __restrict__ rowptr, float* __restrict__ dinv,
                           int* __restrict__ col, int N, int E) {
    extern __shared__ unsigned smem[];
    unsigned* sstage = smem;                 // CSR_CAP words (sd aliases first 1024)
    int* sd   = (int*)smem;
    int* cnt  = (int*)(smem + CSR_CAP);
    int* scur = cnt + BUCK_SIZE;

    int t = threadIdx.x, blk = blockIdx.x;
    cnt[t] = 0;
    __syncthreads();
    int b0 = boff[blk], e1 = boff[blk + 1];
    for (int e = b0 + t; e < e1; e += 1024) atomicAdd(&cnt[packed[e] >> 18], 1);
    __syncthreads();
    int d = cnt[t];
    sd[t] = d;
    __syncthreads();
    for (int off = 1; off < 1024; off <<= 1) {
        int v = (t >= off) ? sd[t - off] : 0;
        __syncthreads();
        sd[t] += v;
        __syncthreads();
    }
    int lstart = sd[t] - d;                  // 0-based within bucket
    int i = (blk << BUCK_SHIFT) + t;
    if (i < N) {
        rowptr[i] = b0 + lstart;
        dinv[i] = rsqrtf((float)(d + 1));    // +1 = self loop
        if (i == N - 1) rowptr[N] = E;
    }
    scur[t] = lstart;
    __syncthreads();                         // all done reading sd before staging overwrites
    for (int e = b0 + t; e < e1; e += 1024) {
        unsigned k = packed[e];
        int pos = atomicAdd(&scur[k >> 18], 1);
        unsigned val = k & 0x3FFFFu;
        if (pos < CSR_CAP) sstage[pos] = val;
        else col[(size_t)b0 + pos] = val;    // overflow fallback (rare)
    }
    __syncthreads();
    int total = e1 - b0;
    int lim = min(total, CSR_CAP);
    for (int j = t; j < lim; j += 1024) col[(size_t)b0 + j] = sstage[j];
}

// ---------------- z0 = dinv * (x @ W_in), interleaved 16-feat fp16 table ----------------

__global__ void z0_kernel(const float* __restrict__ x, const float* __restrict__ W,
                          const float* __restrict__ dinv,
                          __half* __restrict__ z, int n) {
    __shared__ float sW[F_IN * DIM];
    int t = threadIdx.x;
#pragma unroll
    for (int j = 0; j < 4; ++j) sW[t + j * 256] = W[t + j * 256];
    __syncthreads();
    int idx = blockIdx.x * 256 + t;
    if (idx >= n * 2) return;
    int node = idx >> 1, p = idx & 1;
    float acc[8] = {0, 0, 0, 0, 0, 0, 0, 0};
    const float4* xr = (const float4*)(x + (size_t)node * F_IN);
#pragma unroll
    for (int k4 = 0; k4 < 16; ++k4) {
        float4 xv = xr[k4];
        float c[4] = { xv.x, xv.y, xv.z, xv.w };
#pragma unroll
        for (int cc = 0; cc < 4; ++cc) {
            const float* wr = &sW[(k4 * 4 + cc) * DIM + p * 8];
#pragma unroll
            for (int j = 0; j < 8; ++j) acc[j] += c[cc] * wr[j];
        }
    }
    float di = dinv[node];
    __half2 o[4];
#pragma unroll
    for (int m = 0; m < 4; ++m) o[m] = __floats2half2_rn(di * acc[2 * m], di * acc[2 * m + 1]);
    *(float4*)(z + ((size_t)node << 4) + p * 8) = *(float4*)o;
}

// accumulate one 16B half-row (float4 of __half2, already loaded) into a[8]
#define ACC8(v)                                                                \
    {                                                                          \
        const __half2* h_ = (const __half2*)&(v);                              \
        _Pragma("unroll")                                                      \
        for (int m_ = 0; m_ < 4; ++m_) {                                       \
            float2 f_ = __half22float2(h_[m_]);                                \
            a[2 * m_] += f_.x;                                                 \
            a[2 * m_ + 1] += f_.y;                                             \
        }                                                                      \
    }

// ---------------- pair-split gather: 16 lanes/node, 1 line-transaction/edge ----------------
// sub = idx&15; par = sub&1 selects 16B half-row; slot = sub>>1 in [0,8) strides edges.
// MODE 0 : identity epilogue, znext = fp16(di*(r + b))          (layer 0)
// MODE 1 : matmul (1 out-feat/lane) -> o1 + BN partials -> bnsum replica
// MODE 3 : dual matmul + ReLU -> o1, o2 (heads)

template <int MODE>
__launch_bounds__(256)
__global__ void gatherH_kernel(const int* __restrict__ rowptr, const int* __restrict__ col,
                               const __half* __restrict__ z, const float* __restrict__ dinv,
                               const float* __restrict__ Wa, const float* __restrict__ Wb,
                               const float* __restrict__ ba, const float* __restrict__ bb,
                               float* __restrict__ o1, float* __restrict__ o2,
                               __half* __restrict__ znext, float* __restrict__ bnsum, int N) {
    __shared__ float sW[SW_SIZE];
    __shared__ float sred[4][32];
    int t = threadIdx.x;
    if (MODE == 1 || MODE == 3) {
        int f = t >> 4, j = t & 15;
        sW[WA_OFF + WIDX(f, j)] = Wa[t];
        if (MODE == 3) sW[WB_OFF + WIDX(f, j)] = Wb[t];
        if (t < 16) {
            sW[BA_OFF + t] = ba[t];
            if (MODE == 3) sW[BB_OFF + t] = bb[t];
        }
        __syncthreads();
    } else {
        if (t < 16) sW[BA_OFF + t] = ba[t];
        __syncthreads();
    }

    int idx = blockIdx.x * 256 + t;
    int node = idx >> 4, sub = idx & 15;
    int par = sub & 1, slot = sub >> 1;
    bool alive = node < N;
    float a[8];
#pragma unroll
    for (int j = 0; j < 8; ++j) a[j] = 0.f;
    float di = 0.f;
    if (alive) {
        di = dinv[node];
        int start = rowptr[node];
        int len = rowptr[node + 1] - start;
        int k = slot;
        for (; k + 8 < len; k += 16) {         // 2 edges in flight per lane
            int s0 = col[start + k];
            int s1 = col[start + k + 8];
            float4 v0 = *(const float4*)(z + ((size_t)s0 << 4) + par * 8);
            float4 v1 = *(const float4*)(z + ((size_t)s1 << 4) + par * 8);
            ACC8(v0)
            ACC8(v1)
        }
        if (k < len) {
            int s = col[start + k];
            float4 v = *(const float4*)(z + ((size_t)s << 4) + par * 8);
            ACC8(v)
        }
    }
    // reduce over the 8 slots (same parity): xor on sub bits 1..3
#pragma unroll
    for (int j = 0; j < 8; ++j) {
        a[j] += __shfl_xor(a[j], 2);
        a[j] += __shfl_xor(a[j], 4);
        a[j] += __shfl_xor(a[j], 8);
    }
    if (alive) {   // self loop (all lanes of a parity add same value -> consistent)
        float4 v = *(const float4*)(z + ((size_t)node << 4) + par * 8);
        ACC8(v)
    }
    float r[8];
#pragma unroll
    for (int j = 0; j < 8; ++j) r[j] = di * a[j];

    if (MODE == 0) {
        if (alive && slot == 0) {              // sub 0 and 1 write adjacent 16B
            __half2 ov[4];
#pragma unroll
            for (int m = 0; m < 4; ++m) {
                int f = par * 8 + 2 * m;
                ov[m] = __floats2half2_rn(di * (r[2 * m] + sW[BA_OFF + f]),
                                          di * (r[2 * m + 1] + sW[BA_OFF + f + 1]));
            }
            *(float4*)(znext + ((size_t)node << 4) + par * 8) = *(float4*)ov;
        }
        return;
    }

    // parity exchange: assemble full r[16] in every lane (8 shfl)
    float xv[8];
#pragma unroll
    for (int j = 0; j < 8; ++j) xv[j] = __shfl_xor(r[j], 1);
    float rf[16];
#pragma unroll
    for (int f = 0; f < 8; ++f) {
        rf[f] = par ? xv[f] : r[f];
        rf[8 + f] = par ? r[f] : xv[f];
    }
    int j = sub;                               // this lane's output feature
    float oa = sW[BA_OFF + j];
#pragma unroll
    for (int f = 0; f < 16; ++f) oa += rf[f] * sW[WA_OFF + WIDX(f, j)];

    if (MODE == 1) {
        if (alive) o1[((size_t)node << 4) + j] = oa;   // 64B coalesced per node
        float s0 = alive ? oa : 0.f;
        float q0 = s0 * s0;
        s0 += __shfl_xor(s0, 16); q0 += __shfl_xor(q0, 16);
        s0 += __shfl_xor(s0, 32); q0 += __shfl_xor(q0, 32);
        int lane = t & 63, wave = t >> 6;
        if (lane < 16) {
            sred[wave][lane] = s0;
            sred[wave][16 + lane] = q0;
        }
        __syncthreads();
        if (t < 32) {
            float v = sred[0][t] + sred[1][t] + sred[2][t] + sred[3][t];
            atomicAdd(&bnsum[(blockIdx.x & 7) * 32 + t], v);
        }
        return;
    }

    // MODE 3: second head + ReLU, dual coalesced stores
    {
        float ob = sW[BB_OFF + j];
#pragma unroll
        for (int f = 0; f < 16; ++f) ob += rf[f] * sW[WB_OFF + WIDX(f, j)];
        if (alive) {
            o1[((size_t)node << 4) + j] = fmaxf(oa, 0.f);
            o2[((size_t)node << 4) + j] = fmaxf(ob, 0.f);
        }
    }
}

// ---------------- BN finalize (8 replicas -> scale/shift) ----------------

__global__ void bnfin_kernel(const float* __restrict__ bnsum, const float* __restrict__ gamma,
                             const float* __restrict__ beta, float* __restrict__ ssout, int n) {
    int t = threadIdx.x;
    if (t >= 16) return;
    float s = 0.f, sq = 0.f;
#pragma unroll
    for (int rep = 0; rep < 8; ++rep) {
        s += bnsum[rep * 32 + t];
        sq += bnsum[rep * 32 + 16 + t];
    }
    float invN = 1.f / (float)n;
    float mean = s * invN;
    float var = fmaxf(sq * invN - mean * mean, 0.f);
    float scale = gamma[t] * rsqrtf(var + 1e-5f);
    ssout[t] = scale;
    ssout[16 + t] = beta[t] - mean * scale;
}

// ---------------- BN apply + ReLU -> next interleaved z table ----------------

__global__ void bn_relu_z_kernel(const float* __restrict__ hp, const float* __restrict__ ss,
                                 const float* __restrict__ dinv,
                                 __half* __restrict__ z, int n) {
    int idx = blockIdx.x * 256 + threadIdx.x;
    if (idx >= n * 2) return;
    int node = idx >> 1, p = idx & 1;
    float di = dinv[node];
    const float4* hr = (const float4*)(hp + ((size_t)node << 4) + p * 8);
    float4 v0 = hr[0], v1 = hr[1];
    float vv[8] = { v0.x, v0.y, v0.z, v0.w, v1.x, v1.y, v1.z, v1.w };
    __half2 o[4];
#pragma unroll
    for (int m = 0; m < 4; ++m) {
        int f0 = p * 8 + 2 * m;
        float r0 = di * fmaxf(vv[2 * m] * ss[f0] + ss[16 + f0], 0.f);
        float r1 = di * fmaxf(vv[2 * m + 1] * ss[f0 + 1] + ss[16 + f0 + 1], 0.f);
        o[m] = __floats2half2_rn(r0, r1);
    }
    *(float4*)(z + ((size_t)node << 4) + p * 8) = *(float4*)o;
}

// ---------------- launcher ----------------

extern "C" void kernel_launch(void* const* d_in, const int* in_sizes, int n_in,
                              void* d_out, int out_size, void* d_ws, size_t ws_size,
                              hipStream_t stream) {
    (void)n_in; (void)out_size; (void)ws_size;
    const float* x      = (const float*)d_in[0];
    const int*   edge   = (const int*)d_in[1];
    const float* W_in   = (const float*)d_in[2];
    const float* b_in   = (const float*)d_in[3];
    const float* Ws     = (const float*)d_in[4];
    const float* bs     = (const float*)d_in[5];
    const float* gammas = (const float*)d_in[6];
    const float* betas  = (const float*)d_in[7];
    const float* W_sin  = (const float*)d_in[8];
    const float* b_sin  = (const float*)d_in[9];
    const float* W_cos  = (const float*)d_in[10];
    const float* b_cos  = (const float*)d_in[11];
    float* out = (float*)d_out;

    const int N = in_sizes[0] / F_IN;          // 200000
    const int E = in_sizes[1] / 2;             // 6400000
    const int L = in_sizes[4] / (DIM * DIM);   // 4
    const int nb = (N + BUCK_SIZE - 1) >> BUCK_SHIFT;   // 196
    const int* src = edge;
    const int* dst = edge + E;

    char* ws = (char*)d_ws;
    size_t off = 0;
    auto alloc = [&](size_t bytes) { char* p = ws + off; off += (bytes + 15) & ~size_t(15); return p; };
    float*    dinv   = (float*)alloc((size_t)N * 4);
    int*      ghist  = (int*)alloc((size_t)nb * 4);
    int*      boff   = (int*)alloc((size_t)(nb + 1) * 4);
    int*      cursor = (int*)alloc((size_t)nb * 4);
    int*      rowptr = (int*)alloc((size_t)(N + 1) * 4);
    unsigned* packed = (unsigned*)alloc((size_t)E * 4);
    int*      col    = (int*)alloc((size_t)E * 4);
    __half*   zA     = (__half*)alloc((size_t)N * 16 * 2);   // interleaved 32B/node
    __half*   zB     = (__half*)alloc((size_t)N * 16 * 2);
    float*    hp     = (float*)alloc((size_t)N * DIM * 4);
    float*    bnsum  = (float*)alloc((size_t)L * 256 * 4);   // 8 replicas x 32 per layer
    float*    ssbuf  = (float*)alloc((size_t)L * 32 * 4);

    hipMemsetAsync(ghist, 0, (size_t)nb * 4, stream);
    hipMemsetAsync(bnsum, 0, (size_t)L * 256 * 4, stream);

    const int nhist = (E + HIST_CHUNK - 1) / HIST_CHUNK;
    const int nbin  = (E + BIN_CHUNK - 1) / BIN_CHUNK;
    hist_kernel<<<nhist, 256, 0, stream>>>(dst, ghist, E, nb);
    scan_kernel<<<1, 256, 0, stream>>>(ghist, boff, cursor, nb, E);
    bin_kernel<<<nbin, 256, 0, stream>>>(src, dst, cursor, packed, E, nb);
    const size_t csr_lds = (size_t)(CSR_CAP + 2 * BUCK_SIZE) * 4;   // 141312 B
    csr_kernel<<<nb, 1024, csr_lds, stream>>>(packed, boff, rowptr, dinv, col, N, E);

    const int G16 = (N * 16 + 255) / 256;      // gather grid (16 lanes/node)

    // layer 0: z0 then one fused identity-epilogue traversal
    z0_kernel<<<(N * 2 + 255) / 256, 256, 0, stream>>>(x, W_in, dinv, zA, N);
    gatherH_kernel<0><<<G16, 256, 0, stream>>>(rowptr, col, zA, dinv,
                                               nullptr, nullptr, b_in, nullptr,
                                               nullptr, nullptr, zB, nullptr, N);
    __half* cur = zB;
    __half* nxt = zA;

    for (int l = 0; l < L; ++l) {
        gatherH_kernel<1><<<G16, 256, 0, stream>>>(rowptr, col, cur, dinv,
                                                   Ws + l * DIM * DIM, nullptr,
                                                   bs + l * DIM, nullptr,
                                                   hp, nullptr, nullptr,
                                                   bnsum + l * 256, N);
        bnfin_kernel<<<1, 64, 0, stream>>>(bnsum + l * 256, gammas + l * DIM,
                                           betas + l * DIM, ssbuf + l * 32, N);
        bn_relu_z_kernel<<<(N * 2 + 255) / 256, 256, 0, stream>>>(hp, ssbuf + l * 32, dinv,
                                                                  nxt, N);
        __half* tz = cur; cur = nxt; nxt = tz;
    }

    // heads: one traversal, dual epilogue into d_out
    gatherH_kernel<3><<<G16, 256, 0, stream>>>(rowptr, col, cur, dinv,
                                               W_sin, W_cos, b_sin, b_cos,
                                               out, out + (size_t)N * DIM, nullptr,
                                               nullptr, N);
}

// Round 12
// 790.584 us; speedup vs baseline: 1.0153x; 1.0153x over previous
//
#include <hip/hip_runtime.h>
#include <hip/hip_fp16.h>

// RNAGNN round 18: (1) gather reverted to round-13 gatherF (83 us best; r14/r16/r17
// proved the traversal is L2-request-rate bound ~1 req/edge -> ~85 us floor).
// (2) csr occupancy fix: BUCK_SHIFT 10->9 (512-node buckets): 391 blocks x 512
// threads x 70.5 KB LDS -> 2 blocks/CU, all buckets co-resident (was 196 x 1024
// x 141 KB = 1 block/CU on 196/256 CUs, 26% occ). Scans generalized to nb<=512.

#define DIM 16
#define F_IN 64
#define BUCK_SHIFT 9
#define BUCK_SIZE 512
#define NBMAX 512           // nb = ceil(200000/512) = 391
#define HIST_CHUNK 4096
#define BIN_CHUNK 4096
#define EPB 16              // edges per thread in bin (4096/256)
#define CSR_CAP 17024       // staging words: mean 16368 + ~5 sigma; fallback beyond

// LDS weight layout: W[f][j] at f*17+j -> lanes with distinct f hit distinct banks
#define WA_OFF 0
#define WB_OFF 272
#define BA_OFF 544
#define BB_OFF 560
#define SW_SIZE 576
#define WIDX(f, j) ((f) * 17 + (j))

// ---------------- per-bucket edge histogram ----------------

__global__ void hist_kernel(const int* __restrict__ dst, int* __restrict__ ghist,
                            int E, int nb) {
    __shared__ int lh[NBMAX];
    int t = threadIdx.x;
    lh[t] = 0; lh[t + 256] = 0;
    __syncthreads();
    int base = blockIdx.x * HIST_CHUNK;
    int end = min(base + HIST_CHUNK, E);
    for (int e = base + t; e < end; e += 256) atomicAdd(&lh[dst[e] >> BUCK_SHIFT], 1);
    __syncthreads();
    for (int b = t; b < nb; b += 256) {
        int c = lh[b];
        if (c) atomicAdd(&ghist[b], c);
    }
}

// exclusive scan of ghist (nb <= 512, 2 elems/thread) -> boff, cursor
__global__ void scan_kernel(const int* __restrict__ ghist, int* __restrict__ boff,
                            int* __restrict__ cursor, int nb, int E) {
    __shared__ int sd[256];
    int t = threadIdx.x;
    int i0 = 2 * t, i1 = 2 * t + 1;
    int v0 = (i0 < nb) ? ghist[i0] : 0;
    int v1 = (i1 < nb) ? ghist[i1] : 0;
    int s = v0 + v1;
    sd[t] = s;
    __syncthreads();
    for (int off = 1; off < 256; off <<= 1) {
        int u = (t >= off) ? sd[t - off] : 0;
        __syncthreads();
        sd[t] += u;
        __syncthreads();
    }
    int excl = sd[t] - s;
    if (i0 < nb) { boff[i0] = excl; cursor[i0] = excl; }
    if (i1 < nb) { boff[i1] = excl + v0; cursor[i1] = excl + v0; }
    if (t == 255) boff[nb] = E;
}

// pass A: bin edges into dst-range buckets; packed = src | (local_dst << 18).
// LDS bucket-sort within the block, then linear (coalesced) flush to global.
__launch_bounds__(256)
__global__ void bin_kernel(const int* __restrict__ src, const int* __restrict__ dst,
                           int* __restrict__ cursor, unsigned* __restrict__ packed,
                           int E, int nb) {
    __shared__ unsigned sedge[BIN_CHUNK];        // 16 KB sorted packed values
    __shared__ unsigned short sbid[BIN_CHUNK];   // 8 KB bucket id per slot
    __shared__ int lh[NBMAX];
    __shared__ int sd[256];
    __shared__ int lstart[NBMAX];
    __shared__ int lrank[NBMAX];
    __shared__ int gbase[NBMAX];

    int t = threadIdx.x;
    int base = blockIdx.x * BIN_CHUNK;
    int end = min(base + BIN_CHUNK, E);
    lh[t] = 0; lh[t + 256] = 0;
    __syncthreads();

    unsigned pv[EPB];
    int bk[EPB];
#pragma unroll
    for (int i = 0; i < EPB; ++i) {
        int e = base + t + i * 256;
        if (e < end) {
            int d = dst[e];
            int b = d >> BUCK_SHIFT;
            pv[i] = (unsigned)src[e] | ((unsigned)(d & (BUCK_SIZE - 1)) << 18);
            bk[i] = b;
            atomicAdd(&lh[b], 1);
        } else {
            bk[i] = -1;
            pv[i] = 0u;
        }
    }
    __syncthreads();

    // exclusive scan over 512 bucket counts, 2 per thread
    int i0 = 2 * t, i1 = 2 * t + 1;
    int v0 = lh[i0], v1 = lh[i1];
    int s = v0 + v1;
    sd[t] = s;
    __syncthreads();
    for (int off = 1; off < 256; off <<= 1) {
        int u = (t >= off) ? sd[t - off] : 0;
        __syncthreads();
        sd[t] += u;
        __syncthreads();
    }
    int excl = sd[t] - s;
    lstart[i0] = excl;
    lstart[i1] = excl + v0;
    lrank[i0] = 0; lrank[i1] = 0;
    gbase[i0] = v0 ? atomicAdd(&cursor[i0], v0) : 0;
    gbase[i1] = v1 ? atomicAdd(&cursor[i1], v1) : 0;
    __syncthreads();

#pragma unroll
    for (int i = 0; i < EPB; ++i) {
        int b = bk[i];
        if (b >= 0) {
            int rank = atomicAdd(&lrank[b], 1);
            int p = lstart[b] + rank;
            sedge[p] = pv[i];
            sbid[p] = (unsigned short)b;
        }
    }
    __syncthreads();

    int total = end - base;
    for (int j = t; j < total; j += 256) {
        int b = sbid[j];
        packed[(size_t)gbase[b] + (unsigned)(j - lstart[b])] = sedge[j];
    }
}

// pass B: bucket -> exact CSR via LDS staging (coalesced col writes).
// 512 threads/block, 391 blocks, ~70.5 KB dynamic LDS -> 2 blocks/CU.
__launch_bounds__(512)
__global__ void csr_kernel(const unsigned* __restrict__ packed, const int* __restrict__ boff,
                           int* __restrict__ rowptr, float* __restrict__ dinv,
                           int* __restrict__ col, int N, int E) {
    extern __shared__ unsigned smem[];
    unsigned* sstage = smem;                 // CSR_CAP words (sd aliases first 512)
    int* sd   = (int*)smem;
    int* cnt  = (int*)(smem + CSR_CAP);
    int* scur = cnt + BUCK_SIZE;

    int t = threadIdx.x, blk = blockIdx.x;
    cnt[t] = 0;
    __syncthreads();
    int b0 = boff[blk], e1 = boff[blk + 1];
    for (int e = b0 + t; e < e1; e += 512) atomicAdd(&cnt[packed[e] >> 18], 1);
    __syncthreads();
    int d = cnt[t];
    sd[t] = d;
    __syncthreads();
    for (int off = 1; off < 512; off <<= 1) {
        int v = (t >= off) ? sd[t - off] : 0;
        __syncthreads();
        sd[t] += v;
        __syncthreads();
    }
    int lstart = sd[t] - d;                  // 0-based within bucket
    int i = (blk << BUCK_SHIFT) + t;
    if (i < N) {
        rowptr[i] = b0 + lstart;
        dinv[i] = rsqrtf((float)(d + 1));    // +1 = self loop
        if (i == N - 1) rowptr[N] = E;
    }
    scur[t] = lstart;
    __syncthreads();                         // all done reading sd before staging overwrites
    for (int e = b0 + t; e < e1; e += 512) {
        unsigned k = packed[e];
        int pos = atomicAdd(&scur[k >> 18], 1);
        unsigned val = k & 0x3FFFFu;
        if (pos < CSR_CAP) sstage[pos] = val;
        else col[(size_t)b0 + pos] = val;    // overflow fallback (rare)
    }
    __syncthreads();
    int total = e1 - b0;
    int lim = min(total, CSR_CAP);
    for (int j = t; j < lim; j += 512) col[(size_t)b0 + j] = sstage[j];
}

// ---------------- z0 = dinv * (x @ W_in), interleaved 16-feat fp16 table ----------------

__global__ void z0_kernel(const float* __restrict__ x, const float* __restrict__ W,
                          const float* __restrict__ dinv,
                          __half* __restrict__ z, int n) {
    __shared__ float sW[F_IN * DIM];
    int t = threadIdx.x;
#pragma unroll
    for (int j = 0; j < 4; ++j) sW[t + j * 256] = W[t + j * 256];
    __syncthreads();
    int idx = blockIdx.x * 256 + t;
    if (idx >= n * 2) return;
    int node = idx >> 1, p = idx & 1;
    float acc[8] = {0, 0, 0, 0, 0, 0, 0, 0};
    const float4* xr = (const float4*)(x + (size_t)node * F_IN);
#pragma unroll
    for (int k4 = 0; k4 < 16; ++k4) {
        float4 xv = xr[k4];
        float c[4] = { xv.x, xv.y, xv.z, xv.w };
#pragma unroll
        for (int cc = 0; cc < 4; ++cc) {
            const float* wr = &sW[(k4 * 4 + cc) * DIM + p * 8];
#pragma unroll
            for (int j = 0; j < 8; ++j) acc[j] += c[cc] * wr[j];
        }
    }
    float di = dinv[node];
    __half2 o[4];
#pragma unroll
    for (int m = 0; m < 4; ++m) o[m] = __floats2half2_rn(di * acc[2 * m], di * acc[2 * m + 1]);
    *(float4*)(z + ((size_t)node << 4) + p * 8) = *(float4*)o;
}

// ---------------- fused gather: one traversal, full 16-feat rows ----------------
// MODE 0 : identity epilogue, znext = fp16(di*(r + b))          (layer 0)
// MODE 1 : matmul -> o1 (pre-BN fp32) + BN partials -> bnsum replica
// MODE 3 : dual matmul + ReLU -> o1, o2 (heads)

template <int MODE>
__launch_bounds__(256)
__global__ void gatherF_kernel(const int* __restrict__ rowptr, const int* __restrict__ col,
                               const __half* __restrict__ z, const float* __restrict__ dinv,
                               const float* __restrict__ Wa, const float* __restrict__ Wb,
                               const float* __restrict__ ba, const float* __restrict__ bb,
                               float* __restrict__ o1, float* __restrict__ o2,
                               __half* __restrict__ znext, float* __restrict__ bnsum, int N) {
    __shared__ float sW[SW_SIZE];
    __shared__ float sred[4][32];
    int t = threadIdx.x;
    if (MODE == 1 || MODE == 3) {
        int f = t >> 4, j = t & 15;
        sW[WA_OFF + WIDX(f, j)] = Wa[t];
        if (MODE == 3) sW[WB_OFF + WIDX(f, j)] = Wb[t];
        if (t < 16) {
            sW[BA_OFF + t] = ba[t];
            if (MODE == 3) sW[BB_OFF + t] = bb[t];
        }
        __syncthreads();
    } else {
        if (t < 16) sW[BA_OFF + t] = ba[t];
        __syncthreads();
    }

    int idx = blockIdx.x * 256 + t;
    int node = idx >> 3, o = idx & 7;          // 8 lanes per node
    bool alive = node < N;
    float a[16];
#pragma unroll
    for (int j = 0; j < 16; ++j) a[j] = 0.f;
    float di = 0.f;
    if (alive) {
        di = dinv[node];
        int start = rowptr[node];
        int len = rowptr[node + 1] - start;
        int k = o;
        for (; k + 8 < len; k += 16) {         // 2 edges in flight per lane
            int s0 = col[start + k];
            int s1 = col[start + k + 8];
            const float4* q0 = (const float4*)(z + ((size_t)s0 << 4));
            const float4* q1 = (const float4*)(z + ((size_t)s1 << 4));
            float4 v0l = q0[0], v0h = q0[1];
            float4 v1l = q1[0], v1h = q1[1];
            const __half2* h0l = (const __half2*)&v0l;
            const __half2* h0h = (const __half2*)&v0h;
            const __half2* h1l = (const __half2*)&v1l;
            const __half2* h1h = (const __half2*)&v1h;
#pragma unroll
            for (int m = 0; m < 4; ++m) {
                float2 f0 = __half22float2(h0l[m]);
                float2 f1 = __half22float2(h1l[m]);
                a[2 * m] += f0.x + f1.x;
                a[2 * m + 1] += f0.y + f1.y;
                float2 g0 = __half22float2(h0h[m]);
                float2 g1 = __half22float2(h1h[m]);
                a[8 + 2 * m] += g0.x + g1.x;
                a[8 + 2 * m + 1] += g0.y + g1.y;
            }
        }
        if (k < len) {
            int s = col[start + k];
            const float4* q = (const float4*)(z + ((size_t)s << 4));
            float4 vl = q[0], vh = q[1];
            const __half2* hl = (const __half2*)&vl;
            const __half2* hh = (const __half2*)&vh;
#pragma unroll
            for (int m = 0; m < 4; ++m) {
                float2 f2 = __half22float2(hl[m]);
                a[2 * m] += f2.x; a[2 * m + 1] += f2.y;
                float2 g2 = __half22float2(hh[m]);
                a[8 + 2 * m] += g2.x; a[8 + 2 * m + 1] += g2.y;
            }
        }
    }
#pragma unroll
    for (int j = 0; j < 16; ++j) {
        a[j] += __shfl_xor(a[j], 1);
        a[j] += __shfl_xor(a[j], 2);
        a[j] += __shfl_xor(a[j], 4);
    }
    if (alive) {   // self loop (all 8 lanes add same value -> consistent)
        const float4* q = (const float4*)(z + ((size_t)node << 4));
        float4 vl = q[0], vh = q[1];
        const __half2* hl = (const __half2*)&vl;
        const __half2* hh = (const __half2*)&vh;
#pragma unroll
        for (int m = 0; m < 4; ++m) {
            float2 f2 = __half22float2(hl[m]);
            a[2 * m] += f2.x; a[2 * m + 1] += f2.y;
            float2 g2 = __half22float2(hh[m]);
            a[8 + 2 * m] += g2.x; a[8 + 2 * m + 1] += g2.y;
        }
    }
    float r[16];
#pragma unroll
    for (int j = 0; j < 16; ++j) r[j] = di * a[j];

    if (MODE == 0) {
        if (alive && o == 0) {
            __half2 ov[8];
#pragma unroll
            for (int m = 0; m < 8; ++m)
                ov[m] = __floats2half2_rn(di * (r[2 * m] + sW[BA_OFF + 2 * m]),
                                          di * (r[2 * m + 1] + sW[BA_OFF + 2 * m + 1]));
            *(float4*)(znext + ((size_t)node << 4)) = ((float4*)ov)[0];
            *(float4*)(znext + ((size_t)node << 4) + 8) = ((float4*)ov)[1];
        }
        return;
    }

    // MODE 1 / 3: lane o owns input feats {2o, 2o+1} (lane-local, select to
    // avoid runtime-indexed array -> scratch)
    float rc0 = 0.f, rc1 = 0.f;
#pragma unroll
    for (int j = 0; j < 8; ++j)
        if (o == j) { rc0 = r[2 * j]; rc1 = r[2 * j + 1]; }
    if (!alive) { rc0 = 0.f; rc1 = 0.f; }
    int f0 = 2 * o;
    float pa[16];
#pragma unroll
    for (int j = 0; j < 16; ++j)
        pa[j] = rc0 * sW[WA_OFF + WIDX(f0, j)] + rc1 * sW[WA_OFF + WIDX(f0 + 1, j)];
#pragma unroll
    for (int j = 0; j < 16; ++j) {
        pa[j] += __shfl_xor(pa[j], 1);
        pa[j] += __shfl_xor(pa[j], 2);
        pa[j] += __shfl_xor(pa[j], 4);
    }

    if (MODE == 1) {
        float o0 = 0.f, o1v = 0.f;
#pragma unroll
        for (int j = 0; j < 8; ++j)
            if (o == j) {
                o0 = pa[2 * j] + sW[BA_OFF + 2 * j];
                o1v = pa[2 * j + 1] + sW[BA_OFF + 2 * j + 1];
            }
        if (alive)
            *(float2*)(o1 + ((size_t)node << 4) + 2 * o) = make_float2(o0, o1v);
        float s0 = alive ? o0 : 0.f, s1 = alive ? o1v : 0.f;
        float q0 = s0 * s0, q1 = s1 * s1;
#pragma unroll
        for (int m = 8; m <= 32; m <<= 1) {
            s0 += __shfl_xor(s0, m); s1 += __shfl_xor(s1, m);
            q0 += __shfl_xor(q0, m); q1 += __shfl_xor(q1, m);
        }
        int lane = t & 63, wave = t >> 6;
        if (lane < 8) {
            sred[wave][2 * lane] = s0;
            sred[wave][2 * lane + 1] = s1;
            sred[wave][16 + 2 * lane] = q0;
            sred[wave][16 + 2 * lane + 1] = q1;
        }
        __syncthreads();
        if (t < 32) {
            float v = sred[0][t] + sred[1][t] + sred[2][t] + sred[3][t];
            atomicAdd(&bnsum[(blockIdx.x & 7) * 32 + t], v);
        }
        return;
    }

    // MODE 3: dual heads
    {
        float pb[16];
#pragma unroll
        for (int j = 0; j < 16; ++j)
            pb[j] = rc0 * sW[WB_OFF + WIDX(f0, j)] + rc1 * sW[WB_OFF + WIDX(f0 + 1, j)];
#pragma unroll
        for (int j = 0; j < 16; ++j) {
            pb[j] += __shfl_xor(pb[j], 1);
            pb[j] += __shfl_xor(pb[j], 2);
            pb[j] += __shfl_xor(pb[j], 4);
        }
        if (alive) {
            float oa0 = 0.f, oa1 = 0.f, ob0 = 0.f, ob1 = 0.f;
#pragma unroll
            for (int j = 0; j < 8; ++j)
                if (o == j) {
                    oa0 = fmaxf(pa[2 * j] + sW[BA_OFF + 2 * j], 0.f);
                    oa1 = fmaxf(pa[2 * j + 1] + sW[BA_OFF + 2 * j + 1], 0.f);
                    ob0 = fmaxf(pb[2 * j] + sW[BB_OFF + 2 * j], 0.f);
                    ob1 = fmaxf(pb[2 * j + 1] + sW[BB_OFF + 2 * j + 1], 0.f);
                }
            *(float2*)(o1 + ((size_t)node << 4) + 2 * o) = make_float2(oa0, oa1);
            *(float2*)(o2 + ((size_t)node << 4) + 2 * o) = make_float2(ob0, ob1);
        }
    }
}

// ---------------- BN finalize (8 replicas -> scale/shift) ----------------

__global__ void bnfin_kernel(const float* __restrict__ bnsum, const float* __restrict__ gamma,
                             const float* __restrict__ beta, float* __restrict__ ssout, int n) {
    int t = threadIdx.x;
    if (t >= 16) return;
    float s = 0.f, sq = 0.f;
#pragma unroll
    for (int rep = 0; rep < 8; ++rep) {
        s += bnsum[rep * 32 + t];
        sq += bnsum[rep * 32 + 16 + t];
    }
    float invN = 1.f / (float)n;
    float mean = s * invN;
    float var = fmaxf(sq * invN - mean * mean, 0.f);
    float scale = gamma[t] * rsqrtf(var + 1e-5f);
    ssout[t] = scale;
    ssout[16 + t] = beta[t] - mean * scale;
}

// ---------------- BN apply + ReLU -> next interleaved z table ----------------

__global__ void bn_relu_z_kernel(const float* __restrict__ hp, const float* __restrict__ ss,
                                 const float* __restrict__ dinv,
                                 __half* __restrict__ z, int n) {
    int idx = blockIdx.x * 256 + threadIdx.x;
    if (idx >= n * 2) return;
    int node = idx >> 1, p = idx & 1;
    float di = dinv[node];
    const float4* hr = (const float4*)(hp + ((size_t)node << 4) + p * 8);
    float4 v0 = hr[0], v1 = hr[1];
    float vv[8] = { v0.x, v0.y, v0.z, v0.w, v1.x, v1.y, v1.z, v1.w };
    __half2 o[4];
#pragma unroll
    for (int m = 0; m < 4; ++m) {
        int f0 = p * 8 + 2 * m;
        float r0 = di * fmaxf(vv[2 * m] * ss[f0] + ss[16 + f0], 0.f);
        float r1 = di * fmaxf(vv[2 * m + 1] * ss[f0 + 1] + ss[16 + f0 + 1], 0.f);
        o[m] = __floats2half2_rn(r0, r1);
    }
    *(float4*)(z + ((size_t)node << 4) + p * 8) = *(float4*)o;
}

// ---------------- launcher ----------------

extern "C" void kernel_launch(void* const* d_in, const int* in_sizes, int n_in,
                              void* d_out, int out_size, void* d_ws, size_t ws_size,
                              hipStream_t stream) {
    (void)n_in; (void)out_size; (void)ws_size;
    const float* x      = (const float*)d_in[0];
    const int*   edge   = (const int*)d_in[1];
    const float* W_in   = (const float*)d_in[2];
    const float* b_in   = (const float*)d_in[3];
    const float* Ws     = (const float*)d_in[4];
    const float* bs     = (const float*)d_in[5];
    const float* gammas = (const float*)d_in[6];
    const float* betas  = (const float*)d_in[7];
    const float* W_sin  = (const float*)d_in[8];
    const float* b_sin  = (const float*)d_in[9];
    const float* W_cos  = (const float*)d_in[10];
    const float* b_cos  = (const float*)d_in[11];
    float* out = (float*)d_out;

    const int N = in_sizes[0] / F_IN;          // 200000
    const int E = in_sizes[1] / 2;             // 6400000
    const int L = in_sizes[4] / (DIM * DIM);   // 4
    const int nb = (N + BUCK_SIZE - 1) >> BUCK_SHIFT;   // 391
    const int* src = edge;
    const int* dst = edge + E;

    char* ws = (char*)d_ws;
    size_t off = 0;
    auto alloc = [&](size_t bytes) { char* p = ws + off; off += (bytes + 15) & ~size_t(15); return p; };
    float*    dinv   = (float*)alloc((size_t)N * 4);
    int*      ghist  = (int*)alloc((size_t)nb * 4);
    int*      boff   = (int*)alloc((size_t)(nb + 1) * 4);
    int*      cursor = (int*)alloc((size_t)nb * 4);
    int*      rowptr = (int*)alloc((size_t)(N + 1) * 4);
    unsigned* packed = (unsigned*)alloc((size_t)E * 4);
    int*      col    = (int*)alloc((size_t)E * 4);
    __half*   zA     = (__half*)alloc((size_t)N * 16 * 2);   // interleaved 32B/node
    __half*   zB     = (__half*)alloc((size_t)N * 16 * 2);
    float*    hp     = (float*)alloc((size_t)N * DIM * 4);
    float*    bnsum  = (float*)alloc((size_t)L * 256 * 4);   // 8 replicas x 32 per layer
    float*    ssbuf  = (float*)alloc((size_t)L * 32 * 4);

    hipMemsetAsync(ghist, 0, (size_t)nb * 4, stream);
    hipMemsetAsync(bnsum, 0, (size_t)L * 256 * 4, stream);

    const int nhist = (E + HIST_CHUNK - 1) / HIST_CHUNK;
    const int nbin  = (E + BIN_CHUNK - 1) / BIN_CHUNK;
    hist_kernel<<<nhist, 256, 0, stream>>>(dst, ghist, E, nb);
    scan_kernel<<<1, 256, 0, stream>>>(ghist, boff, cursor, nb, E);
    bin_kernel<<<nbin, 256, 0, stream>>>(src, dst, cursor, packed, E, nb);
    const size_t csr_lds = (size_t)(CSR_CAP + 2 * BUCK_SIZE) * 4;   // 72192 B
    csr_kernel<<<nb, 512, csr_lds, stream>>>(packed, boff, rowptr, dinv, col, N, E);

    const int G = (N * 8 + 255) / 256;         // gather grid (8 lanes/node)

    // layer 0: z0 then one fused identity-epilogue traversal
    z0_kernel<<<(N * 2 + 255) / 256, 256, 0, stream>>>(x, W_in, dinv, zA, N);
    gatherF_kernel<0><<<G, 256, 0, stream>>>(rowptr, col, zA, dinv,
                                             nullptr, nullptr, b_in, nullptr,
                                             nullptr, nullptr, zB, nullptr, N);
    __half* cur = zB;
    __half* nxt = zA;

    for (int l = 0; l < L; ++l) {
        gatherF_kernel<1><<<G, 256, 0, stream>>>(rowptr, col, cur, dinv,
                                                 Ws + l * DIM * DIM, nullptr,
                                                 bs + l * DIM, nullptr,
                                                 hp, nullptr, nullptr,
                                                 bnsum + l * 256, N);
        bnfin_kernel<<<1, 64, 0, stream>>>(bnsum + l * 256, gammas + l * DIM,
                                           betas + l * DIM, ssbuf + l * 32, N);
        bn_relu_z_kernel<<<(N * 2 + 255) / 256, 256, 0, stream>>>(hp, ssbuf + l * 32, dinv,
                                                                  nxt, N);
        __half* tz = cur; cur = nxt; nxt = tz;
    }

    // heads: one traversal, dual epilogue into d_out
    gatherF_kernel<3><<<G, 256, 0, stream>>>(rowptr, col, cur, dinv,
                                             W_sin, W_cos, b_sin, b_cos,
                                             out, out + (size_t)N * DIM, nullptr,
                                             nullptr, N);
}

// Round 13
// 679.675 us; speedup vs baseline: 1.1809x; 1.1632x over previous
//
#include <hip/hip_runtime.h>
#include <hip/hip_fp16.h>

// RNAGNN round 19: (1) revert BUCK_SHIFT to 10 / BIN_CHUNK 8192 (r18 lesson:
// flush-run length = BIN_CHUNK/nb must be >= ~32 words; 391 buckets gave 42B
// runs -> WRITE 43MB, bin 87us). (2) ELIMINATE hist_kernel: cursor pre-set to
// fixed-stride regions cursor[b]=b*CAPB (CAPB = mean+7.7sigma); bin reserves
// directly; scan runs AFTER bin (count = cursor-b*CAPB -> boff); csr reads
// packed from b*CAPB, writes col/rowptr at exact boff. Saves a 25.6MB dst pass.

#define DIM 16
#define F_IN 64
#define BUCK_SHIFT 10
#define BUCK_SIZE 1024
#define MAXB 256            // nb = ceil(200000/1024) = 196
#define BIN_CHUNK 8192
#define EPB 32              // edges per thread in bin (8192/256)
#define CSR_CAP 33280       // csr staging words; fallback beyond
#define CAPB 34048          // fixed bucket region stride (mean 32653 + 7.7 sigma)

// LDS weight layout: W[f][j] at f*17+j -> lanes with distinct f hit distinct banks
#define WA_OFF 0
#define WB_OFF 272
#define BA_OFF 544
#define BB_OFF 560
#define SW_SIZE 576
#define WIDX(f, j) ((f) * 17 + (j))

// ---------------- cursor init: fixed-stride bucket regions ----------------

__global__ void initcur_kernel(int* __restrict__ cursor, int nb) {
    int t = threadIdx.x;
    if (t < nb) cursor[t] = t * CAPB;
}

// exclusive scan AFTER bin: counts = cursor[b] - b*CAPB -> boff (nb <= 256)
__global__ void scan_kernel(const int* __restrict__ cursor, int* __restrict__ boff,
                            int nb, int E) {
    __shared__ int sd[256];
    int t = threadIdx.x;
    int v = (t < nb) ? (cursor[t] - t * CAPB) : 0;
    sd[t] = v;
    __syncthreads();
    for (int off = 1; off < 256; off <<= 1) {
        int u = (t >= off) ? sd[t - off] : 0;
        __syncthreads();
        sd[t] += u;
        __syncthreads();
    }
    if (t < nb) boff[t] = sd[t] - v;
    if (t == 255) boff[nb] = E;
}

// pass A: bin edges into dst-range bucket REGIONS; packed = src | (local_dst << 18).
// LDS bucket-sort within the block, then linear (coalesced) flush to global.
__launch_bounds__(256)
__global__ void bin_kernel(const int* __restrict__ src, const int* __restrict__ dst,
                           int* __restrict__ cursor, unsigned* __restrict__ packed,
                           int E, int nb) {
    __shared__ unsigned sedge[BIN_CHUNK];        // 32 KB sorted packed values
    __shared__ unsigned char sbid[BIN_CHUNK];    // 8 KB bucket id per slot
    __shared__ int lh[MAXB];
    __shared__ int sd[MAXB];
    __shared__ int lstart[MAXB];
    __shared__ int lrank[MAXB];
    __shared__ int gbase[MAXB];

    int t = threadIdx.x;
    int base = blockIdx.x * BIN_CHUNK;
    int end = min(base + BIN_CHUNK, E);
    lh[t] = 0;
    __syncthreads();

    unsigned pv[EPB];
    int bk[EPB];
#pragma unroll
    for (int i = 0; i < EPB; ++i) {
        int e = base + t + i * 256;
        if (e < end) {
            int d = dst[e];
            int b = d >> BUCK_SHIFT;
            pv[i] = (unsigned)src[e] | ((unsigned)(d & (BUCK_SIZE - 1)) << 18);
            bk[i] = b;
            atomicAdd(&lh[b], 1);
        } else {
            bk[i] = -1;
            pv[i] = 0u;
        }
    }
    __syncthreads();

    int v = (t < nb) ? lh[t] : 0;
    sd[t] = v;
    __syncthreads();
    for (int off = 1; off < 256; off <<= 1) {
        int u = (t >= off) ? sd[t - off] : 0;
        __syncthreads();
        sd[t] += u;
        __syncthreads();
    }
    if (t < nb) {
        lstart[t] = sd[t] - v;
        lrank[t] = 0;
        gbase[t] = v ? atomicAdd(&cursor[t], v) : 0;
    }
    __syncthreads();

#pragma unroll
    for (int i = 0; i < EPB; ++i) {
        int b = bk[i];
        if (b >= 0) {
            int rank = atomicAdd(&lrank[b], 1);
            int p = lstart[b] + rank;
            sedge[p] = pv[i];
            sbid[p] = (unsigned char)b;
        }
    }
    __syncthreads();

    int total = end - base;
    for (int j = t; j < total; j += 256) {
        int b = sbid[j];
        packed[(size_t)gbase[b] + (unsigned)(j - lstart[b])] = sedge[j];
    }
}

// pass B: bucket region -> exact CSR via LDS staging (coalesced col writes).
// Dynamic LDS: sstage[CSR_CAP] (sd aliases it) + cnt[1024] + scur[1024].
__launch_bounds__(1024)
__global__ void csr_kernel(const unsigned* __restrict__ packed, const int* __restrict__ boff,
                           int* __restrict__ rowptr, float* __restrict__ dinv,
                           int* __restrict__ col, int N, int E) {
    extern __shared__ unsigned smem[];
    unsigned* sstage = smem;                 // CSR_CAP words (sd aliases first 1024)
    int* sd   = (int*)smem;
    int* cnt  = (int*)(smem + CSR_CAP);
    int* scur = cnt + BUCK_SIZE;

    int t = threadIdx.x, blk = blockIdx.x;
    cnt[t] = 0;
    __syncthreads();
    int b0 = boff[blk], e1 = boff[blk + 1];
    int total = e1 - b0;
    const unsigned* pk = packed + (size_t)blk * CAPB;
    for (int e = t; e < total; e += 1024) atomicAdd(&cnt[pk[e] >> 18], 1);
    __syncthreads();
    int d = cnt[t];
    sd[t] = d;
    __syncthreads();
    for (int off = 1; off < 1024; off <<= 1) {
        int v = (t >= off) ? sd[t - off] : 0;
        __syncthreads();
        sd[t] += v;
        __syncthreads();
    }
    int lstart = sd[t] - d;                  // 0-based within bucket
    int i = (blk << BUCK_SHIFT) + t;
    if (i < N) {
        rowptr[i] = b0 + lstart;
        dinv[i] = rsqrtf((float)(d + 1));    // +1 = self loop
        if (i == N - 1) rowptr[N] = E;
    }
    scur[t] = lstart;
    __syncthreads();                         // all done reading sd before staging overwrites
    for (int e = t; e < total; e += 1024) {
        unsigned k = pk[e];
        int pos = atomicAdd(&scur[k >> 18], 1);
        unsigned val = k & 0x3FFFFu;
        if (pos < CSR_CAP) sstage[pos] = val;
        else col[(size_t)b0 + pos] = val;    // overflow fallback (rare)
    }
    __syncthreads();
    int lim = min(total, CSR_CAP);
    for (int j = t; j < lim; j += 1024) col[(size_t)b0 + j] = sstage[j];
}

// ---------------- z0 = dinv * (x @ W_in), interleaved 16-feat fp16 table ----------------

__global__ void z0_kernel(const float* __restrict__ x, const float* __restrict__ W,
                          const float* __restrict__ dinv,
                          __half* __restrict__ z, int n) {
    __shared__ float sW[F_IN * DIM];
    int t = threadIdx.x;
#pragma unroll
    for (int j = 0; j < 4; ++j) sW[t + j * 256] = W[t + j * 256];
    __syncthreads();
    int idx = blockIdx.x * 256 + t;
    if (idx >= n * 2) return;
    int node = idx >> 1, p = idx & 1;
    float acc[8] = {0, 0, 0, 0, 0, 0, 0, 0};
    const float4* xr = (const float4*)(x + (size_t)node * F_IN);
#pragma unroll
    for (int k4 = 0; k4 < 16; ++k4) {
        float4 xv = xr[k4];
        float c[4] = { xv.x, xv.y, xv.z, xv.w };
#pragma unroll
        for (int cc = 0; cc < 4; ++cc) {
            const float* wr = &sW[(k4 * 4 + cc) * DIM + p * 8];
#pragma unroll
            for (int j = 0; j < 8; ++j) acc[j] += c[cc] * wr[j];
        }
    }
    float di = dinv[node];
    __half2 o[4];
#pragma unroll
    for (int m = 0; m < 4; ++m) o[m] = __floats2half2_rn(di * acc[2 * m], di * acc[2 * m + 1]);
    *(float4*)(z + ((size_t)node << 4) + p * 8) = *(float4*)o;
}

// ---------------- fused gather: one traversal, full 16-feat rows ----------------
// MODE 0 : identity epilogue, znext = fp16(di*(r + b))          (layer 0)
// MODE 1 : matmul -> o1 (pre-BN fp32) + BN partials -> bnsum replica
// MODE 3 : dual matmul + ReLU -> o1, o2 (heads)

template <int MODE>
__launch_bounds__(256)
__global__ void gatherF_kernel(const int* __restrict__ rowptr, const int* __restrict__ col,
                               const __half* __restrict__ z, const float* __restrict__ dinv,
                               const float* __restrict__ Wa, const float* __restrict__ Wb,
                               const float* __restrict__ ba, const float* __restrict__ bb,
                               float* __restrict__ o1, float* __restrict__ o2,
                               __half* __restrict__ znext, float* __restrict__ bnsum, int N) {
    __shared__ float sW[SW_SIZE];
    __shared__ float sred[4][32];
    int t = threadIdx.x;
    if (MODE == 1 || MODE == 3) {
        int f = t >> 4, j = t & 15;
        sW[WA_OFF + WIDX(f, j)] = Wa[t];
        if (MODE == 3) sW[WB_OFF + WIDX(f, j)] = Wb[t];
        if (t < 16) {
            sW[BA_OFF + t] = ba[t];
            if (MODE == 3) sW[BB_OFF + t] = bb[t];
        }
        __syncthreads();
    } else {
        if (t < 16) sW[BA_OFF + t] = ba[t];
        __syncthreads();
    }

    int idx = blockIdx.x * 256 + t;
    int node = idx >> 3, o = idx & 7;          // 8 lanes per node
    bool alive = node < N;
    float a[16];
#pragma unroll
    for (int j = 0; j < 16; ++j) a[j] = 0.f;
    float di = 0.f;
    if (alive) {
        di = dinv[node];
        int start = rowptr[node];
        int len = rowptr[node + 1] - start;
        int k = o;
        for (; k + 8 < len; k += 16) {         // 2 edges in flight per lane
            int s0 = col[start + k];
            int s1 = col[start + k + 8];
            const float4* q0 = (const float4*)(z + ((size_t)s0 << 4));
            const float4* q1 = (const float4*)(z + ((size_t)s1 << 4));
            float4 v0l = q0[0], v0h = q0[1];
            float4 v1l = q1[0], v1h = q1[1];
            const __half2* h0l = (const __half2*)&v0l;
            const __half2* h0h = (const __half2*)&v0h;
            const __half2* h1l = (const __half2*)&v1l;
            const __half2* h1h = (const __half2*)&v1h;
#pragma unroll
            for (int m = 0; m < 4; ++m) {
                float2 f0 = __half22float2(h0l[m]);
                float2 f1 = __half22float2(h1l[m]);
                a[2 * m] += f0.x + f1.x;
                a[2 * m + 1] += f0.y + f1.y;
                float2 g0 = __half22float2(h0h[m]);
                float2 g1 = __half22float2(h1h[m]);
                a[8 + 2 * m] += g0.x + g1.x;
                a[8 + 2 * m + 1] += g0.y + g1.y;
            }
        }
        if (k < len) {
            int s = col[start + k];
            const float4* q = (const float4*)(z + ((size_t)s << 4));
            float4 vl = q[0], vh = q[1];
            const __half2* hl = (const __half2*)&vl;
            const __half2* hh = (const __half2*)&vh;
#pragma unroll
            for (int m = 0; m < 4; ++m) {
                float2 f2 = __half22float2(hl[m]);
                a[2 * m] += f2.x; a[2 * m + 1] += f2.y;
                float2 g2 = __half22float2(hh[m]);
                a[8 + 2 * m] += g2.x; a[8 + 2 * m + 1] += g2.y;
            }
        }
    }
#pragma unroll
    for (int j = 0; j < 16; ++j) {
        a[j] += __shfl_xor(a[j], 1);
        a[j] += __shfl_xor(a[j], 2);
        a[j] += __shfl_xor(a[j], 4);
    }
    if (alive) {   // self loop (all 8 lanes add same value -> consistent)
        const float4* q = (const float4*)(z + ((size_t)node << 4));
        float4 vl = q[0], vh = q[1];
        const __half2* hl = (const __half2*)&vl;
        const __half2* hh = (const __half2*)&vh;
#pragma unroll
        for (int m = 0; m < 4; ++m) {
            float2 f2 = __half22float2(hl[m]);
            a[2 * m] += f2.x; a[2 * m + 1] += f2.y;
            float2 g2 = __half22float2(hh[m]);
            a[8 + 2 * m] += g2.x; a[8 + 2 * m + 1] += g2.y;
        }
    }
    float r[16];
#pragma unroll
    for (int j = 0; j < 16; ++j) r[j] = di * a[j];

    if (MODE == 0) {
        if (alive && o == 0) {
            __half2 ov[8];
#pragma unroll
            for (int m = 0; m < 8; ++m)
                ov[m] = __floats2half2_rn(di * (r[2 * m] + sW[BA_OFF + 2 * m]),
                                          di * (r[2 * m + 1] + sW[BA_OFF + 2 * m + 1]));
            *(float4*)(znext + ((size_t)node << 4)) = ((float4*)ov)[0];
            *(float4*)(znext + ((size_t)node << 4) + 8) = ((float4*)ov)[1];
        }
        return;
    }

    // MODE 1 / 3: lane o owns input feats {2o, 2o+1} (lane-local, select to
    // avoid runtime-indexed array -> scratch)
    float rc0 = 0.f, rc1 = 0.f;
#pragma unroll
    for (int j = 0; j < 8; ++j)
        if (o == j) { rc0 = r[2 * j]; rc1 = r[2 * j + 1]; }
    if (!alive) { rc0 = 0.f; rc1 = 0.f; }
    int f0 = 2 * o;
    float pa[16];
#pragma unroll
    for (int j = 0; j < 16; ++j)
        pa[j] = rc0 * sW[WA_OFF + WIDX(f0, j)] + rc1 * sW[WA_OFF + WIDX(f0 + 1, j)];
#pragma unroll
    for (int j = 0; j < 16; ++j) {
        pa[j] += __shfl_xor(pa[j], 1);
        pa[j] += __shfl_xor(pa[j], 2);
        pa[j] += __shfl_xor(pa[j], 4);
    }

    if (MODE == 1) {
        float o0 = 0.f, o1v = 0.f;
#pragma unroll
        for (int j = 0; j < 8; ++j)
            if (o == j) {
                o0 = pa[2 * j] + sW[BA_OFF + 2 * j];
                o1v = pa[2 * j + 1] + sW[BA_OFF + 2 * j + 1];
            }
        if (alive)
            *(float2*)(o1 + ((size_t)node << 4) + 2 * o) = make_float2(o0, o1v);
        float s0 = alive ? o0 : 0.f, s1 = alive ? o1v : 0.f;
        float q0 = s0 * s0, q1 = s1 * s1;
#pragma unroll
        for (int m = 8; m <= 32; m <<= 1) {
            s0 += __shfl_xor(s0, m); s1 += __shfl_xor(s1, m);
            q0 += __shfl_xor(q0, m); q1 += __shfl_xor(q1, m);
        }
        int lane = t & 63, wave = t >> 6;
        if (lane < 8) {
            sred[wave][2 * lane] = s0;
            sred[wave][2 * lane + 1] = s1;
            sred[wave][16 + 2 * lane] = q0;
            sred[wave][16 + 2 * lane + 1] = q1;
        }
        __syncthreads();
        if (t < 32) {
            float v = sred[0][t] + sred[1][t] + sred[2][t] + sred[3][t];
            atomicAdd(&bnsum[(blockIdx.x & 7) * 32 + t], v);
        }
        return;
    }

    // MODE 3: dual heads
    {
        float pb[16];
#pragma unroll
        for (int j = 0; j < 16; ++j)
            pb[j] = rc0 * sW[WB_OFF + WIDX(f0, j)] + rc1 * sW[WB_OFF + WIDX(f0 + 1, j)];
#pragma unroll
        for (int j = 0; j < 16; ++j) {
            pb[j] += __shfl_xor(pb[j], 1);
            pb[j] += __shfl_xor(pb[j], 2);
            pb[j] += __shfl_xor(pb[j], 4);
        }
        if (alive) {
            float oa0 = 0.f, oa1 = 0.f, ob0 = 0.f, ob1 = 0.f;
#pragma unroll
            for (int j = 0; j < 8; ++j)
                if (o == j) {
                    oa0 = fmaxf(pa[2 * j] + sW[BA_OFF + 2 * j], 0.f);
                    oa1 = fmaxf(pa[2 * j + 1] + sW[BA_OFF + 2 * j + 1], 0.f);
                    ob0 = fmaxf(pb[2 * j] + sW[BB_OFF + 2 * j], 0.f);
                    ob1 = fmaxf(pb[2 * j + 1] + sW[BB_OFF + 2 * j + 1], 0.f);
                }
            *(float2*)(o1 + ((size_t)node << 4) + 2 * o) = make_float2(oa0, oa1);
            *(float2*)(o2 + ((size_t)node << 4) + 2 * o) = make_float2(ob0, ob1);
        }
    }
}

// ---------------- BN finalize (8 replicas -> scale/shift) ----------------

__global__ void bnfin_kernel(const float* __restrict__ bnsum, const float* __restrict__ gamma,
                             const float* __restrict__ beta, float* __restrict__ ssout, int n) {
    int t = threadIdx.x;
    if (t >= 16) return;
    float s = 0.f, sq = 0.f;
#pragma unroll
    for (int rep = 0; rep < 8; ++rep) {
        s += bnsum[rep * 32 + t];
        sq += bnsum[rep * 32 + 16 + t];
    }
    float invN = 1.f / (float)n;
    float mean = s * invN;
    float var = fmaxf(sq * invN - mean * mean, 0.f);
    float scale = gamma[t] * rsqrtf(var + 1e-5f);
    ssout[t] = scale;
    ssout[16 + t] = beta[t] - mean * scale;
}

// ---------------- BN apply + ReLU -> next interleaved z table ----------------

__global__ void bn_relu_z_kernel(const float* __restrict__ hp, const float* __restrict__ ss,
                                 const float* __restrict__ dinv,
                                 __half* __restrict__ z, int n) {
    int idx = blockIdx.x * 256 + threadIdx.x;
    if (idx >= n * 2) return;
    int node = idx >> 1, p = idx & 1;
    float di = dinv[node];
    const float4* hr = (const float4*)(hp + ((size_t)node << 4) + p * 8);
    float4 v0 = hr[0], v1 = hr[1];
    float vv[8] = { v0.x, v0.y, v0.z, v0.w, v1.x, v1.y, v1.z, v1.w };
    __half2 o[4];
#pragma unroll
    for (int m = 0; m < 4; ++m) {
        int f0 = p * 8 + 2 * m;
        float r0 = di * fmaxf(vv[2 * m] * ss[f0] + ss[16 + f0], 0.f);
        float r1 = di * fmaxf(vv[2 * m + 1] * ss[f0 + 1] + ss[16 + f0 + 1], 0.f);
        o[m] = __floats2half2_rn(r0, r1);
    }
    *(float4*)(z + ((size_t)node << 4) + p * 8) = *(float4*)o;
}

// ---------------- launcher ----------------

extern "C" void kernel_launch(void* const* d_in, const int* in_sizes, int n_in,
                              void* d_out, int out_size, void* d_ws, size_t ws_size,
                              hipStream_t stream) {
    (void)n_in; (void)out_size; (void)ws_size;
    const float* x      = (const float*)d_in[0];
    const int*   edge   = (const int*)d_in[1];
    const float* W_in   = (const float*)d_in[2];
    const float* b_in   = (const float*)d_in[3];
    const float* Ws     = (const float*)d_in[4];
    const float* bs     = (const float*)d_in[5];
    const float* gammas = (const float*)d_in[6];
    const float* betas  = (const float*)d_in[7];
    const float* W_sin  = (const float*)d_in[8];
    const float* b_sin  = (const float*)d_in[9];
    const float* W_cos  = (const float*)d_in[10];
    const float* b_cos  = (const float*)d_in[11];
    float* out = (float*)d_out;

    const int N = in_sizes[0] / F_IN;          // 200000
    const int E = in_sizes[1] / 2;             // 6400000
    const int L = in_sizes[4] / (DIM * DIM);   // 4
    const int nb = (N + BUCK_SIZE - 1) >> BUCK_SHIFT;   // 196
    const int* src = edge;
    const int* dst = edge + E;

    char* ws = (char*)d_ws;
    size_t off = 0;
    auto alloc = [&](size_t bytes) { char* p = ws + off; off += (bytes + 15) & ~size_t(15); return p; };
    float*    dinv   = (float*)alloc((size_t)N * 4);
    int*      boff   = (int*)alloc((size_t)(nb + 1) * 4);
    int*      cursor = (int*)alloc((size_t)nb * 4);
    int*      rowptr = (int*)alloc((size_t)(N + 1) * 4);
    unsigned* packed = (unsigned*)alloc((size_t)nb * CAPB * 4);   // region-strided
    int*      col    = (int*)alloc((size_t)E * 4);
    __half*   zA     = (__half*)alloc((size_t)N * 16 * 2);   // interleaved 32B/node
    __half*   zB     = (__half*)alloc((size_t)N * 16 * 2);
    float*    hp     = (float*)alloc((size_t)N * DIM * 4);
    float*    bnsum  = (float*)alloc((size_t)L * 256 * 4);   // 8 replicas x 32 per layer
    float*    ssbuf  = (float*)alloc((size_t)L * 32 * 4);

    hipMemsetAsync(bnsum, 0, (size_t)L * 256 * 4, stream);

    const int nbin = (E + BIN_CHUNK - 1) / BIN_CHUNK;
    initcur_kernel<<<1, 256, 0, stream>>>(cursor, nb);
    bin_kernel<<<nbin, 256, 0, stream>>>(src, dst, cursor, packed, E, nb);
    scan_kernel<<<1, 256, 0, stream>>>(cursor, boff, nb, E);
    const size_t csr_lds = (size_t)(CSR_CAP + 2 * BUCK_SIZE) * 4;   // 141312 B
    csr_kernel<<<nb, 1024, csr_lds, stream>>>(packed, boff, rowptr, dinv, col, N, E);

    const int G = (N * 8 + 255) / 256;         // gather grid (8 lanes/node)

    // layer 0: z0 then one fused identity-epilogue traversal
    z0_kernel<<<(N * 2 + 255) / 256, 256, 0, stream>>>(x, W_in, dinv, zA, N);
    gatherF_kernel<0><<<G, 256, 0, stream>>>(rowptr, col, zA, dinv,
                                             nullptr, nullptr, b_in, nullptr,
                                             nullptr, nullptr, zB, nullptr, N);
    __half* cur = zB;
    __half* nxt = zA;

    for (int l = 0; l < L; ++l) {
        gatherF_kernel<1><<<G, 256, 0, stream>>>(rowptr, col, cur, dinv,
                                                 Ws + l * DIM * DIM, nullptr,
                                                 bs + l * DIM, nullptr,
                                                 hp, nullptr, nullptr,
                                                 bnsum + l * 256, N);
        bnfin_kernel<<<1, 64, 0, stream>>>(bnsum + l * 256, gammas + l * DIM,
                                           betas + l * DIM, ssbuf + l * 32, N);
        bn_relu_z_kernel<<<(N * 2 + 255) / 256, 256, 0, stream>>>(hp, ssbuf + l * 32, dinv,
                                                                  nxt, N);
        __half* tz = cur; cur = nxt; nxt = tz;
    }

    // heads: one traversal, dual epilogue into d_out
    gatherF_kernel<3><<<G, 256, 0, stream>>>(rowptr, col, cur, dinv,
                                             W_sin, W_cos, b_sin, b_cos,
                                             out, out + (size_t)N * DIM, nullptr,
                                             nullptr, N);
}

// Round 14
// 663.049 us; speedup vs baseline: 1.2105x; 1.0251x over previous
//
#include <hip/hip_runtime.h>
#include <hip/hip_fp16.h>

// RNAGNN round 20: preprocessing de-barrier. bin -> 512 threads (24 waves/CU,
// was 12); Hillis-Steele scans in bin (256-wide) and csr (1024-wide) replaced
// with __shfl_up wave scans + wave-sum combine (2 barriers instead of 16-20).
// csr no longer aliases scan workspace with staging. Gather/z0/bn untouched
// (gather is at its L2-request-rate floor ~80 us/traversal, r14/r16/r17).

#define DIM 16
#define F_IN 64
#define BUCK_SHIFT 10
#define BUCK_SIZE 1024
#define MAXB 256            // nb = ceil(200000/1024) = 196
#define BIN_CHUNK 8192
#define EPB 16              // edges per thread in bin (8192/512)
#define CSR_CAP 33280       // csr staging words; fallback beyond
#define CAPB 34048          // fixed bucket region stride (mean 32653 + 7.7 sigma)

// LDS weight layout: W[f][j] at f*17+j -> lanes with distinct f hit distinct banks
#define WA_OFF 0
#define WB_OFF 272
#define BA_OFF 544
#define BB_OFF 560
#define SW_SIZE 576
#define WIDX(f, j) ((f) * 17 + (j))

// ---------------- cursor init: fixed-stride bucket regions ----------------

__global__ void initcur_kernel(int* __restrict__ cursor, int nb) {
    int t = threadIdx.x;
    if (t < nb) cursor[t] = t * CAPB;
}

// exclusive scan AFTER bin: counts = cursor[b] - b*CAPB -> boff (nb <= 256)
__global__ void scan_kernel(const int* __restrict__ cursor, int* __restrict__ boff,
                            int nb, int E) {
    __shared__ int sd[256];
    int t = threadIdx.x;
    int v = (t < nb) ? (cursor[t] - t * CAPB) : 0;
    sd[t] = v;
    __syncthreads();
    for (int off = 1; off < 256; off <<= 1) {
        int u = (t >= off) ? sd[t - off] : 0;
        __syncthreads();
        sd[t] += u;
        __syncthreads();
    }
    if (t < nb) boff[t] = sd[t] - v;
    if (t == 255) boff[nb] = E;
}

// pass A: bin edges into dst-range bucket REGIONS; packed = src | (local_dst << 18).
// 512 threads; LDS bucket-sort then linear (coalesced) flush.
__launch_bounds__(512)
__global__ void bin_kernel(const int* __restrict__ src, const int* __restrict__ dst,
                           int* __restrict__ cursor, unsigned* __restrict__ packed,
                           int E, int nb) {
    __shared__ unsigned sedge[BIN_CHUNK];        // 32 KB sorted packed values
    __shared__ unsigned char sbid[BIN_CHUNK];    // 8 KB bucket id per slot
    __shared__ int lh[MAXB];
    __shared__ int lstart[MAXB];
    __shared__ int lrank[MAXB];
    __shared__ int gbase[MAXB];
    __shared__ int wsum8[8];

    int t = threadIdx.x;
    int base = blockIdx.x * BIN_CHUNK;
    int end = min(base + BIN_CHUNK, E);
    if (t < MAXB) lh[t] = 0;
    __syncthreads();

    unsigned pv[EPB];
    int bk[EPB];
#pragma unroll
    for (int i = 0; i < EPB; ++i) {
        int e = base + t + i * 512;
        if (e < end) {
            int d = dst[e];
            int b = d >> BUCK_SHIFT;
            pv[i] = (unsigned)src[e] | ((unsigned)(d & (BUCK_SIZE - 1)) << 18);
            bk[i] = b;
            atomicAdd(&lh[b], 1);
        } else {
            bk[i] = -1;
            pv[i] = 0u;
        }
    }
    __syncthreads();

    // wave-shuffle exclusive scan over 256 bucket counts (threads 0..255)
    int lane = t & 63, wave = t >> 6;
    int v = (t < MAXB) ? lh[t] : 0;
    int s = v;
#pragma unroll
    for (int off = 1; off < 64; off <<= 1) {
        int u = __shfl_up(s, off);
        if (lane >= off) s += u;
    }
    if (t < MAXB && lane == 63) wsum8[wave] = s;
    __syncthreads();
    if (t < MAXB) {
        int pre = 0;
#pragma unroll
        for (int w = 0; w < 4; ++w) pre += (w < wave) ? wsum8[w] : 0;
        lstart[t] = pre + s - v;
        lrank[t] = 0;
        gbase[t] = v ? atomicAdd(&cursor[t], v) : 0;
    }
    __syncthreads();

#pragma unroll
    for (int i = 0; i < EPB; ++i) {
        int b = bk[i];
        if (b >= 0) {
            int rank = atomicAdd(&lrank[b], 1);
            int p = lstart[b] + rank;
            sedge[p] = pv[i];
            sbid[p] = (unsigned char)b;
        }
    }
    __syncthreads();

    int total = end - base;
    for (int j = t; j < total; j += 512) {
        int b = sbid[j];
        packed[(size_t)gbase[b] + (unsigned)(j - lstart[b])] = sedge[j];
    }
}

// pass B: bucket region -> exact CSR via LDS staging (coalesced col writes).
// Dynamic LDS: sstage[CSR_CAP] + cnt[1024] + scur[1024]; wave-shuffle scan.
__launch_bounds__(1024)
__global__ void csr_kernel(const unsigned* __restrict__ packed, const int* __restrict__ boff,
                           int* __restrict__ rowptr, float* __restrict__ dinv,
                           int* __restrict__ col, int N, int E) {
    extern __shared__ unsigned smem[];
    unsigned* sstage = smem;                 // CSR_CAP words
    int* cnt  = (int*)(smem + CSR_CAP);
    int* scur = cnt + BUCK_SIZE;
    __shared__ int wsum16[16];

    int t = threadIdx.x, blk = blockIdx.x;
    cnt[t] = 0;
    __syncthreads();
    int b0 = boff[blk], e1 = boff[blk + 1];
    int total = e1 - b0;
    const unsigned* pk = packed + (size_t)blk * CAPB;
    for (int e = t; e < total; e += 1024) atomicAdd(&cnt[pk[e] >> 18], 1);
    __syncthreads();

    // wave-shuffle exclusive scan over 1024 node counts
    int lane = t & 63, wave = t >> 6;
    int d = cnt[t];
    int s = d;
#pragma unroll
    for (int off = 1; off < 64; off <<= 1) {
        int u = __shfl_up(s, off);
        if (lane >= off) s += u;
    }
    if (lane == 63) wsum16[wave] = s;
    __syncthreads();
    int pre = 0;
#pragma unroll
    for (int w = 0; w < 16; ++w) pre += (w < wave) ? wsum16[w] : 0;
    int lstart = pre + s - d;                // 0-based within bucket
    int i = (blk << BUCK_SHIFT) + t;
    if (i < N) {
        rowptr[i] = b0 + lstart;
        dinv[i] = rsqrtf((float)(d + 1));    // +1 = self loop
        if (i == N - 1) rowptr[N] = E;
    }
    scur[t] = lstart;
    __syncthreads();
    for (int e = t; e < total; e += 1024) {
        unsigned k = pk[e];
        int pos = atomicAdd(&scur[k >> 18], 1);
        unsigned val = k & 0x3FFFFu;
        if (pos < CSR_CAP) sstage[pos] = val;
        else col[(size_t)b0 + pos] = val;    // overflow fallback (rare)
    }
    __syncthreads();
    int lim = min(total, CSR_CAP);
    for (int j = t; j < lim; j += 1024) col[(size_t)b0 + j] = sstage[j];
}

// ---------------- z0 = dinv * (x @ W_in), interleaved 16-feat fp16 table ----------------

__global__ void z0_kernel(const float* __restrict__ x, const float* __restrict__ W,
                          const float* __restrict__ dinv,
                          __half* __restrict__ z, int n) {
    __shared__ float sW[F_IN * DIM];
    int t = threadIdx.x;
#pragma unroll
    for (int j = 0; j < 4; ++j) sW[t + j * 256] = W[t + j * 256];
    __syncthreads();
    int idx = blockIdx.x * 256 + t;
    if (idx >= n * 2) return;
    int node = idx >> 1, p = idx & 1;
    float acc[8] = {0, 0, 0, 0, 0, 0, 0, 0};
    const float4* xr = (const float4*)(x + (size_t)node * F_IN);
#pragma unroll
    for (int k4 = 0; k4 < 16; ++k4) {
        float4 xv = xr[k4];
        float c[4] = { xv.x, xv.y, xv.z, xv.w };
#pragma unroll
        for (int cc = 0; cc < 4; ++cc) {
            const float* wr = &sW[(k4 * 4 + cc) * DIM + p * 8];
#pragma unroll
            for (int j = 0; j < 8; ++j) acc[j] += c[cc] * wr[j];
        }
    }
    float di = dinv[node];
    __half2 o[4];
#pragma unroll
    for (int m = 0; m < 4; ++m) o[m] = __floats2half2_rn(di * acc[2 * m], di * acc[2 * m + 1]);
    *(float4*)(z + ((size_t)node << 4) + p * 8) = *(float4*)o;
}

// ---------------- fused gather: one traversal, full 16-feat rows ----------------
// MODE 0 : identity epilogue, znext = fp16(di*(r + b))          (layer 0)
// MODE 1 : matmul -> o1 (pre-BN fp32) + BN partials -> bnsum replica
// MODE 3 : dual matmul + ReLU -> o1, o2 (heads)

template <int MODE>
__launch_bounds__(256)
__global__ void gatherF_kernel(const int* __restrict__ rowptr, const int* __restrict__ col,
                               const __half* __restrict__ z, const float* __restrict__ dinv,
                               const float* __restrict__ Wa, const float* __restrict__ Wb,
                               const float* __restrict__ ba, const float* __restrict__ bb,
                               float* __restrict__ o1, float* __restrict__ o2,
                               __half* __restrict__ znext, float* __restrict__ bnsum, int N) {
    __shared__ float sW[SW_SIZE];
    __shared__ float sred[4][32];
    int t = threadIdx.x;
    if (MODE == 1 || MODE == 3) {
        int f = t >> 4, j = t & 15;
        sW[WA_OFF + WIDX(f, j)] = Wa[t];
        if (MODE == 3) sW[WB_OFF + WIDX(f, j)] = Wb[t];
        if (t < 16) {
            sW[BA_OFF + t] = ba[t];
            if (MODE == 3) sW[BB_OFF + t] = bb[t];
        }
        __syncthreads();
    } else {
        if (t < 16) sW[BA_OFF + t] = ba[t];
        __syncthreads();
    }

    int idx = blockIdx.x * 256 + t;
    int node = idx >> 3, o = idx & 7;          // 8 lanes per node
    bool alive = node < N;
    float a[16];
#pragma unroll
    for (int j = 0; j < 16; ++j) a[j] = 0.f;
    float di = 0.f;
    if (alive) {
        di = dinv[node];
        int start = rowptr[node];
        int len = rowptr[node + 1] - start;
        int k = o;
        for (; k + 8 < len; k += 16) {         // 2 edges in flight per lane
            int s0 = col[start + k];
            int s1 = col[start + k + 8];
            const float4* q0 = (const float4*)(z + ((size_t)s0 << 4));
            const float4* q1 = (const float4*)(z + ((size_t)s1 << 4));
            float4 v0l = q0[0], v0h = q0[1];
            float4 v1l = q1[0], v1h = q1[1];
            const __half2* h0l = (const __half2*)&v0l;
            const __half2* h0h = (const __half2*)&v0h;
            const __half2* h1l = (const __half2*)&v1l;
            const __half2* h1h = (const __half2*)&v1h;
#pragma unroll
            for (int m = 0; m < 4; ++m) {
                float2 f0 = __half22float2(h0l[m]);
                float2 f1 = __half22float2(h1l[m]);
                a[2 * m] += f0.x + f1.x;
                a[2 * m + 1] += f0.y + f1.y;
                float2 g0 = __half22float2(h0h[m]);
                float2 g1 = __half22float2(h1h[m]);
                a[8 + 2 * m] += g0.x + g1.x;
                a[8 + 2 * m + 1] += g0.y + g1.y;
            }
        }
        if (k < len) {
            int s = col[start + k];
            const float4* q = (const float4*)(z + ((size_t)s << 4));
            float4 vl = q[0], vh = q[1];
            const __half2* hl = (const __half2*)&vl;
            const __half2* hh = (const __half2*)&vh;
#pragma unroll
            for (int m = 0; m < 4; ++m) {
                float2 f2 = __half22float2(hl[m]);
                a[2 * m] += f2.x; a[2 * m + 1] += f2.y;
                float2 g2 = __half22float2(hh[m]);
                a[8 + 2 * m] += g2.x; a[8 + 2 * m + 1] += g2.y;
            }
        }
    }
#pragma unroll
    for (int j = 0; j < 16; ++j) {
        a[j] += __shfl_xor(a[j], 1);
        a[j] += __shfl_xor(a[j], 2);
        a[j] += __shfl_xor(a[j], 4);
    }
    if (alive) {   // self loop (all 8 lanes add same value -> consistent)
        const float4* q = (const float4*)(z + ((size_t)node << 4));
        float4 vl = q[0], vh = q[1];
        const __half2* hl = (const __half2*)&vl;
        const __half2* hh = (const __half2*)&vh;
#pragma unroll
        for (int m = 0; m < 4; ++m) {
            float2 f2 = __half22float2(hl[m]);
            a[2 * m] += f2.x; a[2 * m + 1] += f2.y;
            float2 g2 = __half22float2(hh[m]);
            a[8 + 2 * m] += g2.x; a[8 + 2 * m + 1] += g2.y;
        }
    }
    float r[16];
#pragma unroll
    for (int j = 0; j < 16; ++j) r[j] = di * a[j];

    if (MODE == 0) {
        if (alive && o == 0) {
            __half2 ov[8];
#pragma unroll
            for (int m = 0; m < 8; ++m)
                ov[m] = __floats2half2_rn(di * (r[2 * m] + sW[BA_OFF + 2 * m]),
                                          di * (r[2 * m + 1] + sW[BA_OFF + 2 * m + 1]));
            *(float4*)(znext + ((size_t)node << 4)) = ((float4*)ov)[0];
            *(float4*)(znext + ((size_t)node << 4) + 8) = ((float4*)ov)[1];
        }
        return;
    }

    // MODE 1 / 3: lane o owns input feats {2o, 2o+1} (lane-local, select to
    // avoid runtime-indexed array -> scratch)
    float rc0 = 0.f, rc1 = 0.f;
#pragma unroll
    for (int j = 0; j < 8; ++j)
        if (o == j) { rc0 = r[2 * j]; rc1 = r[2 * j + 1]; }
    if (!alive) { rc0 = 0.f; rc1 = 0.f; }
    int f0 = 2 * o;
    float pa[16];
#pragma unroll
    for (int j = 0; j < 16; ++j)
        pa[j] = rc0 * sW[WA_OFF + WIDX(f0, j)] + rc1 * sW[WA_OFF + WIDX(f0 + 1, j)];
#pragma unroll
    for (int j = 0; j < 16; ++j) {
        pa[j] += __shfl_xor(pa[j], 1);
        pa[j] += __shfl_xor(pa[j], 2);
        pa[j] += __shfl_xor(pa[j], 4);
    }

    if (MODE == 1) {
        float o0 = 0.f, o1v = 0.f;
#pragma unroll
        for (int j = 0; j < 8; ++j)
            if (o == j) {
                o0 = pa[2 * j] + sW[BA_OFF + 2 * j];
                o1v = pa[2 * j + 1] + sW[BA_OFF + 2 * j + 1];
            }
        if (alive)
            *(float2*)(o1 + ((size_t)node << 4) + 2 * o) = make_float2(o0, o1v);
        float s0 = alive ? o0 : 0.f, s1 = alive ? o1v : 0.f;
        float q0 = s0 * s0, q1 = s1 * s1;
#pragma unroll
        for (int m = 8; m <= 32; m <<= 1) {
            s0 += __shfl_xor(s0, m); s1 += __shfl_xor(s1, m);
            q0 += __shfl_xor(q0, m); q1 += __shfl_xor(q1, m);
        }
        int lane = t & 63, wave = t >> 6;
        if (lane < 8) {
            sred[wave][2 * lane] = s0;
            sred[wave][2 * lane + 1] = s1;
            sred[wave][16 + 2 * lane] = q0;
            sred[wave][16 + 2 * lane + 1] = q1;
        }
        __syncthreads();
        if (t < 32) {
            float v = sred[0][t] + sred[1][t] + sred[2][t] + sred[3][t];
            atomicAdd(&bnsum[(blockIdx.x & 7) * 32 + t], v);
        }
        return;
    }

    // MODE 3: dual heads
    {
        float pb[16];
#pragma unroll
        for (int j = 0; j < 16; ++j)
            pb[j] = rc0 * sW[WB_OFF + WIDX(f0, j)] + rc1 * sW[WB_OFF + WIDX(f0 + 1, j)];
#pragma unroll
        for (int j = 0; j < 16; ++j) {
            pb[j] += __shfl_xor(pb[j], 1);
            pb[j] += __shfl_xor(pb[j], 2);
            pb[j] += __shfl_xor(pb[j], 4);
        }
        if (alive) {
            float oa0 = 0.f, oa1 = 0.f, ob0 = 0.f, ob1 = 0.f;
#pragma unroll
            for (int j = 0; j < 8; ++j)
                if (o == j) {
                    oa0 = fmaxf(pa[2 * j] + sW[BA_OFF + 2 * j], 0.f);
                    oa1 = fmaxf(pa[2 * j + 1] + sW[BA_OFF + 2 * j + 1], 0.f);
                    ob0 = fmaxf(pb[2 * j] + sW[BB_OFF + 2 * j], 0.f);
                    ob1 = fmaxf(pb[2 * j + 1] + sW[BB_OFF + 2 * j + 1], 0.f);
                }
            *(float2*)(o1 + ((size_t)node << 4) + 2 * o) = make_float2(oa0, oa1);
            *(float2*)(o2 + ((size_t)node << 4) + 2 * o) = make_float2(ob0, ob1);
        }
    }
}

// ---------------- BN finalize (8 replicas -> scale/shift) ----------------

__global__ void bnfin_kernel(const float* __restrict__ bnsum, const float* __restrict__ gamma,
                             const float* __restrict__ beta, float* __restrict__ ssout, int n) {
    int t = threadIdx.x;
    if (t >= 16) return;
    float s = 0.f, sq = 0.f;
#pragma unroll
    for (int rep = 0; rep < 8; ++rep) {
        s += bnsum[rep * 32 + t];
        sq += bnsum[rep * 32 + 16 + t];
    }
    float invN = 1.f / (float)n;
    float mean = s * invN;
    float var = fmaxf(sq * invN - mean * mean, 0.f);
    float scale = gamma[t] * rsqrtf(var + 1e-5f);
    ssout[t] = scale;
    ssout[16 + t] = beta[t] - mean * scale;
}

// ---------------- BN apply + ReLU -> next interleaved z table ----------------

__global__ void bn_relu_z_kernel(const float* __restrict__ hp, const float* __restrict__ ss,
                                 const float* __restrict__ dinv,
                                 __half* __restrict__ z, int n) {
    int idx = blockIdx.x * 256 + threadIdx.x;
    if (idx >= n * 2) return;
    int node = idx >> 1, p = idx & 1;
    float di = dinv[node];
    const float4* hr = (const float4*)(hp + ((size_t)node << 4) + p * 8);
    float4 v0 = hr[0], v1 = hr[1];
    float vv[8] = { v0.x, v0.y, v0.z, v0.w, v1.x, v1.y, v1.z, v1.w };
    __half2 o[4];
#pragma unroll
    for (int m = 0; m < 4; ++m) {
        int f0 = p * 8 + 2 * m;
        float r0 = di * fmaxf(vv[2 * m] * ss[f0] + ss[16 + f0], 0.f);
        float r1 = di * fmaxf(vv[2 * m + 1] * ss[f0 + 1] + ss[16 + f0 + 1], 0.f);
        o[m] = __floats2half2_rn(r0, r1);
    }
    *(float4*)(z + ((size_t)node << 4) + p * 8) = *(float4*)o;
}

// ---------------- launcher ----------------

extern "C" void kernel_launch(void* const* d_in, const int* in_sizes, int n_in,
                              void* d_out, int out_size, void* d_ws, size_t ws_size,
                              hipStream_t stream) {
    (void)n_in; (void)out_size; (void)ws_size;
    const float* x      = (const float*)d_in[0];
    const int*   edge   = (const int*)d_in[1];
    const float* W_in   = (const float*)d_in[2];
    const float* b_in   = (const float*)d_in[3];
    const float* Ws     = (const float*)d_in[4];
    const float* bs     = (const float*)d_in[5];
    const float* gammas = (const float*)d_in[6];
    const float* betas  = (const float*)d_in[7];
    const float* W_sin  = (const float*)d_in[8];
    const float* b_sin  = (const float*)d_in[9];
    const float* W_cos  = (const float*)d_in[10];
    const float* b_cos  = (const float*)d_in[11];
    float* out = (float*)d_out;

    const int N = in_sizes[0] / F_IN;          // 200000
    const int E = in_sizes[1] / 2;             // 6400000
    const int L = in_sizes[4] / (DIM * DIM);   // 4
    const int nb = (N + BUCK_SIZE - 1) >> BUCK_SHIFT;   // 196
    const int* src = edge;
    const int* dst = edge + E;

    char* ws = (char*)d_ws;
    size_t off = 0;
    auto alloc = [&](size_t bytes) { char* p = ws + off; off += (bytes + 15) & ~size_t(15); return p; };
    float*    dinv   = (float*)alloc((size_t)N * 4);
    int*      boff   = (int*)alloc((size_t)(nb + 1) * 4);
    int*      cursor = (int*)alloc((size_t)nb * 4);
    int*      rowptr = (int*)alloc((size_t)(N + 1) * 4);
    unsigned* packed = (unsigned*)alloc((size_t)nb * CAPB * 4);   // region-strided
    int*      col    = (int*)alloc((size_t)E * 4);
    __half*   zA     = (__half*)alloc((size_t)N * 16 * 2);   // interleaved 32B/node
    __half*   zB     = (__half*)alloc((size_t)N * 16 * 2);
    float*    hp     = (float*)alloc((size_t)N * DIM * 4);
    float*    bnsum  = (float*)alloc((size_t)L * 256 * 4);   // 8 replicas x 32 per layer
    float*    ssbuf  = (float*)alloc((size_t)L * 32 * 4);

    hipMemsetAsync(bnsum, 0, (size_t)L * 256 * 4, stream);

    const int nbin = (E + BIN_CHUNK - 1) / BIN_CHUNK;
    initcur_kernel<<<1, 256, 0, stream>>>(cursor, nb);
    bin_kernel<<<nbin, 512, 0, stream>>>(src, dst, cursor, packed, E, nb);
    scan_kernel<<<1, 256, 0, stream>>>(cursor, boff, nb, E);
    const size_t csr_lds = (size_t)(CSR_CAP + 2 * BUCK_SIZE) * 4;   // 141312 B
    csr_kernel<<<nb, 1024, csr_lds, stream>>>(packed, boff, rowptr, dinv, col, N, E);

    const int G = (N * 8 + 255) / 256;         // gather grid (8 lanes/node)

    // layer 0: z0 then one fused identity-epilogue traversal
    z0_kernel<<<(N * 2 + 255) / 256, 256, 0, stream>>>(x, W_in, dinv, zA, N);
    gatherF_kernel<0><<<G, 256, 0, stream>>>(rowptr, col, zA, dinv,
                                             nullptr, nullptr, b_in, nullptr,
                                             nullptr, nullptr, zB, nullptr, N);
    __half* cur = zB;
    __half* nxt = zA;

    for (int l = 0; l < L; ++l) {
        gatherF_kernel<1><<<G, 256, 0, stream>>>(rowptr, col, cur, dinv,
                                                 Ws + l * DIM * DIM, nullptr,
                                                 bs + l * DIM, nullptr,
                                                 hp, nullptr, nullptr,
                                                 bnsum + l * 256, N);
        bnfin_kernel<<<1, 64, 0, stream>>>(bnsum + l * 256, gammas + l * DIM,
                                           betas + l * DIM, ssbuf + l * 32, N);
        bn_relu_z_kernel<<<(N * 2 + 255) / 256, 256, 0, stream>>>(hp, ssbuf + l * 32, dinv,
                                                                  nxt, N);
        __half* tz = cur; cur = nxt; nxt = tz;
    }

    // heads: one traversal, dual epilogue into d_out
    gatherF_kernel<3><<<G, 256, 0, stream>>>(rowptr, col, cur, dinv,
                                             W_sin, W_cos, b_sin, b_cos,
                                             out, out + (size_t)N * DIM, nullptr,
                                             nullptr, N);
}